// Round 1
// baseline (278.722 us; speedup 1.0000x reference)
//
#include <hip/hip_runtime.h>
#include <hip/hip_bf16.h>
#include <math.h>

#define CUTOFFV 5.0f
#define NRAD 6
#define EMB 128
#define NTYPES 95
#define PI_F 3.14159265358979323846f

typedef short short8 __attribute__((ext_vector_type(8)));
typedef float f32x4 __attribute__((ext_vector_type(4)));

__device__ __forceinline__ unsigned short f2bf(float f) {
    union { float f; unsigned int u; } v; v.f = f;
    unsigned int u = v.u;
    unsigned int r = (u + 0x7FFFu + ((u >> 16) & 1u)) >> 16;
    return (unsigned short)r;
}

__device__ __forceinline__ float silu_f(float x) {
    return x / (1.0f + __expf(-x));
}

// ---------------- prep: P1 = emb@W1^T + b_dense, P2 = emb@W2^T, W3 -> bf16 ----
__global__ void prep_kernel(const float* __restrict__ emb,
                            const float* __restrict__ Wd,
                            const float* __restrict__ bd,
                            float* __restrict__ P1, float* __restrict__ P2,
                            unsigned short* __restrict__ W3b) {
    int b = blockIdx.x, tid = threadIdx.x;
    if (b < 2 * NTYPES) {
        int t = b / NTYPES, z = b % NTYPES;
        __shared__ float emb_s[EMB];
        emb_s[tid] = emb[z * EMB + tid];
        __syncthreads();
        float acc = (t == 0) ? bd[tid] : 0.0f;
        const float* wrow = Wd + (size_t)tid * 384 + t * EMB;
        #pragma unroll 8
        for (int j = 0; j < EMB; ++j) acc += emb_s[j] * wrow[j];
        (t == 0 ? P1 : P2)[z * EMB + tid] = acc;
    } else {
        int g = (b - 2 * NTYPES) * 128 + tid;   // 0..1023
        for (int i = g; i < EMB * EMB; i += 8 * 128) {
            int n = i >> 7, k = i & 127;
            W3b[i] = f2bf(Wd[(size_t)n * 384 + 256 + k]);
        }
    }
}

// ---------------- h output: gather rows of emb_table --------------------------
__global__ void h_kernel(const int* __restrict__ Z, const float* __restrict__ emb,
                         float* __restrict__ out_h, int N) {
    int idx = blockIdx.x * 256 + threadIdx.x;  // float4 index
    int total = N * (EMB / 4);
    if (idx >= total) return;
    int v = idx >> 5, c = idx & 31;            // 32 float4 per row
    int z = Z[v];
    const float4* e4 = (const float4*)emb;
    float4* o4 = (float4*)out_h;
    o4[idx] = e4[z * 32 + c];
}

// ---------------- edge kernel: 64 edges per 256-thread block ------------------
__global__ void __launch_bounds__(256)
edge_kernel(const int* __restrict__ Z, const int* __restrict__ src,
            const int* __restrict__ dst, const float* __restrict__ rbf,
            const float* __restrict__ dvec, const float* __restrict__ Wr,
            const float* __restrict__ brbf, const float* __restrict__ P1,
            const float* __restrict__ P2, const unsigned short* __restrict__ W3b,
            float* __restrict__ out_m, float* __restrict__ out_env, int E) {
    __shared__ unsigned char A_lds[64 * EMB * 2];   // bf16, XOR-swizzled rows
    __shared__ float rbf_s[64 * NRAD];
    __shared__ float Wr_s[EMB * NRAD];
    __shared__ float brbf_s[EMB];
    __shared__ int zs_s[64], zd_s[64];

    const int tid = threadIdx.x;
    const int e0 = blockIdx.x * 64;

    // ---- stage small operands ----
    for (int i = tid; i < EMB * NRAD; i += 256) Wr_s[i] = Wr[i];
    if (tid < EMB) brbf_s[tid] = brbf[tid];
    for (int i = tid; i < 64 * NRAD; i += 256) {
        int gi = e0 * NRAD + i;
        rbf_s[i] = (gi < E * NRAD) ? rbf[gi] : 0.0f;
    }
    if (tid < 64) {
        int e = e0 + tid;
        int ec = (e < E) ? e : (E - 1);
        zs_s[tid] = Z[src[ec]];
        zd_s[tid] = Z[dst[ec]];
    }
    __syncthreads();

    // ---- compute rbf_proj tile -> bf16 swizzled LDS ----
    // thread owns edge (tid&63); wave shares k -> Wr_s reads are broadcasts
    {
        const int e = tid & 63;
        const float r0 = rbf_s[e * 6 + 0], r1 = rbf_s[e * 6 + 1],
                    r2 = rbf_s[e * 6 + 2], r3 = rbf_s[e * 6 + 3],
                    r4 = rbf_s[e * 6 + 4], r5 = rbf_s[e * 6 + 5];
        #pragma unroll
        for (int i = 0; i < 4; ++i) {
            int kc = (tid >> 6) + 4 * i;   // 0..15
            int k0 = kc * 8;
            short8 pk;
            #pragma unroll
            for (int j = 0; j < 8; ++j) {
                int k = k0 + j;
                const float* w = &Wr_s[k * 6];
                float pre = brbf_s[k] + r0 * w[0] + r1 * w[1] + r2 * w[2] +
                            r3 * w[3] + r4 * w[4] + r5 * w[5];
                pk[j] = (short)f2bf(silu_f(pre));
            }
            int off = (e * 256 + k0 * 2) ^ ((e & 7) << 4);
            *(short8*)(A_lds + off) = pk;
        }
    }
    __syncthreads();

    // ---- MFMA: [64 x 128] = A[64 x 128] * W3^T, bf16 in / f32 acc ----
    const int w = tid >> 6;      // wave 0..3 owns n in [32w, 32w+32)
    const int l = tid & 63;
    const int lr = l & 15;
    const int lg = l >> 4;

    short8 bfrag[2][4];
    #pragma unroll
    for (int nt = 0; nt < 2; ++nt) {
        int n = w * 32 + nt * 16 + lr;
        #pragma unroll
        for (int ks = 0; ks < 4; ++ks) {
            int k0 = ks * 32 + lg * 8;
            bfrag[nt][ks] = *(const short8*)(W3b + n * EMB + k0);
        }
    }

    f32x4 acc[4][2];
    #pragma unroll
    for (int mt = 0; mt < 4; ++mt)
        #pragma unroll
        for (int nt = 0; nt < 2; ++nt)
            acc[mt][nt] = (f32x4){0.f, 0.f, 0.f, 0.f};

    #pragma unroll
    for (int ks = 0; ks < 4; ++ks) {
        int k0 = ks * 32 + lg * 8;
        short8 afrag[4];
        #pragma unroll
        for (int mt = 0; mt < 4; ++mt) {
            int row = mt * 16 + lr;
            int off = (row * 256 + k0 * 2) ^ ((row & 7) << 4);
            afrag[mt] = *(const short8*)(A_lds + off);
        }
        #pragma unroll
        for (int mt = 0; mt < 4; ++mt)
            #pragma unroll
            for (int nt = 0; nt < 2; ++nt)
                acc[mt][nt] = __builtin_amdgcn_mfma_f32_16x16x32_bf16(
                    afrag[mt], bfrag[nt][ks], acc[mt][nt], 0, 0, 0);
    }

    // ---- epilogue: + P1[z_src] + P2[z_dst] (bias folded in P1), silu, store --
    #pragma unroll
    for (int mt = 0; mt < 4; ++mt) {
        #pragma unroll
        for (int nt = 0; nt < 2; ++nt) {
            int n = w * 32 + nt * 16 + lr;
            #pragma unroll
            for (int r = 0; r < 4; ++r) {
                int el = mt * 16 + lg * 4 + r;
                int e = e0 + el;
                if (e < E) {
                    float v = acc[mt][nt][r] + P1[zs_s[el] * EMB + n] +
                              P2[zd_s[el] * EMB + n];
                    out_m[(size_t)e * EMB + n] = silu_f(v);
                }
            }
        }
    }

    // ---- rbf_env (bessel * envelope) ----
    for (int i = tid; i < 64 * NRAD; i += 256) {
        int el = i / 6, r = i - el * 6;
        int e = e0 + el;
        if (e < E) {
            float x = dvec[e] * (1.0f / CUTOFFV);
            float inv = 1.0f / x;
            float x2 = x * x;
            float x5 = x2 * x2 * x;
            float env = inv + x5 * (-28.0f + x * (48.0f - 21.0f * x));
            float s = sinf(x * PI_F * (float)(r + 1));
            out_env[(size_t)e * 6 + r] = env * s * inv;
        }
    }
}

extern "C" void kernel_launch(void* const* d_in, const int* in_sizes, int n_in,
                              void* d_out, int out_size, void* d_ws, size_t ws_size,
                              hipStream_t stream) {
    const int* Z = (const int*)d_in[0];
    const int* src = (const int*)d_in[1];
    const int* dst = (const int*)d_in[2];
    const float* rbf = (const float*)d_in[3];
    const float* dvec = (const float*)d_in[4];
    const float* emb = (const float*)d_in[5];
    const float* Wr = (const float*)d_in[6];
    const float* brbf = (const float*)d_in[7];
    const float* Wd = (const float*)d_in[8];
    const float* bd = (const float*)d_in[9];

    const int N = in_sizes[0];
    const int E = in_sizes[1];

    float* out_h = (float*)d_out;
    float* out_m = out_h + (size_t)N * EMB;
    float* out_env = out_m + (size_t)E * EMB;

    // workspace: P1 (95*128 f32) | P2 (95*128 f32) | W3 bf16 (128*128)
    float* P1 = (float*)d_ws;
    float* P2 = P1 + NTYPES * EMB;
    unsigned short* W3b = (unsigned short*)(P2 + NTYPES * EMB);

    prep_kernel<<<2 * NTYPES + 8, 128, 0, stream>>>(emb, Wd, bd, P1, P2, W3b);

    int hblocks = (N * (EMB / 4) + 255) / 256;
    h_kernel<<<hblocks, 256, 0, stream>>>(Z, emb, out_h, N);

    int eblocks = (E + 63) / 64;
    edge_kernel<<<eblocks, 256, 0, stream>>>(Z, src, dst, rbf, dvec, Wr, brbf,
                                             P1, P2, W3b, out_m, out_env, E);
}

// Round 2
// 236.516 us; speedup vs baseline: 1.1784x; 1.1784x over previous
//
#include <hip/hip_runtime.h>
#include <hip/hip_bf16.h>
#include <math.h>

#define CUTOFFV 5.0f
#define NRAD 6
#define EMB 128
#define NTYPES 95
#define PI_F 3.14159265358979323846f

typedef short short8 __attribute__((ext_vector_type(8)));
typedef float f32x4 __attribute__((ext_vector_type(4)));

__device__ __forceinline__ unsigned short f2bf(float f) {
    union { float f; unsigned int u; } v; v.f = f;
    unsigned int u = v.u;
    unsigned int r = (u + 0x7FFFu + ((u >> 16) & 1u)) >> 16;
    return (unsigned short)r;
}

__device__ __forceinline__ float fast_rcp(float x) {
    float y;
    asm("v_rcp_f32 %0, %1" : "=v"(y) : "v"(x));
    return y;
}

// silu via hardware rcp (1 ulp) instead of precise-division sequence
__device__ __forceinline__ float silu_f(float x) {
    return x * fast_rcp(1.0f + __expf(-x));
}

// ---------------- prep: P1 = emb@W1^T + b_dense, P2 = emb@W2^T, W3 -> bf16 ----
__global__ void prep_kernel(const float* __restrict__ emb,
                            const float* __restrict__ Wd,
                            const float* __restrict__ bd,
                            float* __restrict__ P1, float* __restrict__ P2,
                            unsigned short* __restrict__ W3b) {
    int b = blockIdx.x, tid = threadIdx.x;
    if (b < 2 * NTYPES) {
        int t = b / NTYPES, z = b % NTYPES;
        __shared__ float emb_s[EMB];
        emb_s[tid] = emb[z * EMB + tid];
        __syncthreads();
        float acc = (t == 0) ? bd[tid] : 0.0f;
        const float* wrow = Wd + (size_t)tid * 384 + t * EMB;
        #pragma unroll 8
        for (int j = 0; j < EMB; ++j) acc += emb_s[j] * wrow[j];
        (t == 0 ? P1 : P2)[z * EMB + tid] = acc;
    } else {
        int g = (b - 2 * NTYPES) * 128 + tid;   // 0..1023
        for (int i = g; i < EMB * EMB; i += 8 * 128) {
            int n = i >> 7, k = i & 127;
            W3b[i] = f2bf(Wd[(size_t)n * 384 + 256 + k]);
        }
    }
}

// ---------------- h output: gather rows of emb_table --------------------------
__global__ void h_kernel(const int* __restrict__ Z, const float* __restrict__ emb,
                         float* __restrict__ out_h, int N) {
    int idx = blockIdx.x * 256 + threadIdx.x;  // float4 index
    int total = N * (EMB / 4);
    if (idx >= total) return;
    int v = idx >> 5, c = idx & 31;            // 32 float4 per row
    int z = Z[v];
    const float4* e4 = (const float4*)emb;
    float4* o4 = (float4*)out_h;
    o4[idx] = e4[z * 32 + c];
}

// ---------------- edge kernel: 64 edges per 256-thread block ------------------
__global__ void __launch_bounds__(256, 4)
edge_kernel(const int* __restrict__ Z, const int* __restrict__ src,
            const int* __restrict__ dst, const float* __restrict__ rbf,
            const float* __restrict__ dvec, const float* __restrict__ Wr,
            const float* __restrict__ brbf, const float* __restrict__ P1,
            const float* __restrict__ P2, const unsigned short* __restrict__ W3b,
            float* __restrict__ out_m, float* __restrict__ out_env, int E) {
    __shared__ unsigned char A_lds[64 * EMB * 2];   // bf16, XOR-swizzled rows
    __shared__ float rbf_s[64 * NRAD];
    __shared__ float Wr_s[EMB * NRAD];
    __shared__ float brbf_s[EMB];
    __shared__ int zs_s[64], zd_s[64];

    const int tid = threadIdx.x;
    const int e0 = blockIdx.x * 64;

    // ---- stage small operands ----
    for (int i = tid; i < EMB * NRAD; i += 256) Wr_s[i] = Wr[i];
    if (tid < EMB) brbf_s[tid] = brbf[tid];
    for (int i = tid; i < 64 * NRAD; i += 256) {
        int gi = e0 * NRAD + i;
        rbf_s[i] = (gi < E * NRAD) ? rbf[gi] : 0.0f;
    }
    if (tid < 64) {
        int e = e0 + tid;
        int ec = (e < E) ? e : (E - 1);
        zs_s[tid] = Z[src[ec]];
        zd_s[tid] = Z[dst[ec]];
    }

    // ---- rbf_env: one thread per edge, sincos + Chebyshev recurrence ----
    if (tid < 64) {
        int e = e0 + tid;
        if (e < E) {
            float x = dvec[e] * (1.0f / CUTOFFV);      // d_scaled in (0,1]
            float inv = fast_rcp(x);
            float x2 = x * x;
            float x5 = x2 * x2 * x;
            float env = inv + x5 * (-28.0f + x * (48.0f - 21.0f * x));
            float s1, c1;
            __sincosf(PI_F * x, &s1, &c1);
            float twoc = 2.0f * c1;
            float f = env * inv;
            float sp = 0.0f, sc = s1;                   // s_0, s_1
            float* o = out_env + (size_t)e * 6;
            #pragma unroll
            for (int r = 0; r < NRAD; ++r) {
                o[r] = f * sc;
                float sn = twoc * sc - sp;
                sp = sc; sc = sn;
            }
        }
    }
    __syncthreads();

    // ---- compute rbf_proj tile -> bf16 swizzled LDS ----
    // thread owns edge (tid&63); wave shares k -> Wr_s reads are broadcasts
    {
        const int e = tid & 63;
        const float r0 = rbf_s[e * 6 + 0], r1 = rbf_s[e * 6 + 1],
                    r2 = rbf_s[e * 6 + 2], r3 = rbf_s[e * 6 + 3],
                    r4 = rbf_s[e * 6 + 4], r5 = rbf_s[e * 6 + 5];
        #pragma unroll
        for (int i = 0; i < 4; ++i) {
            int kc = (tid >> 6) + 4 * i;   // 0..15
            int k0 = kc * 8;
            short8 pk;
            #pragma unroll
            for (int j = 0; j < 8; ++j) {
                int k = k0 + j;
                const float* w = &Wr_s[k * 6];
                float pre = brbf_s[k] + r0 * w[0] + r1 * w[1] + r2 * w[2] +
                            r3 * w[3] + r4 * w[4] + r5 * w[5];
                pk[j] = (short)f2bf(silu_f(pre));
            }
            int off = (e * 256 + k0 * 2) ^ ((e & 7) << 4);
            *(short8*)(A_lds + off) = pk;
        }
    }
    __syncthreads();

    // ---- MFMA with SWAPPED operands: D[n, edge] = W3[n,:] . rbfproj[edge,:] --
    // a-operand = W3 fragment (M-dim = n), b-operand = edge tile (N-dim = edge)
    // C layout: col(lane&15) = edge, row((lane>>4)*4+r) = n  -> lane holds 4
    // consecutive n for ONE edge -> float4 stores + float4 P1/P2 loads.
    const int w = tid >> 6;      // wave w owns n in [32w, 32w+32)
    const int l = tid & 63;
    const int lr = l & 15;
    const int lg = l >> 4;

    short8 wfrag[2][4];
    #pragma unroll
    for (int nt = 0; nt < 2; ++nt) {
        int n = w * 32 + nt * 16 + lr;
        #pragma unroll
        for (int ks = 0; ks < 4; ++ks) {
            int k0 = ks * 32 + lg * 8;
            wfrag[nt][ks] = *(const short8*)(W3b + n * EMB + k0);
        }
    }

    #pragma unroll
    for (int et = 0; et < 4; ++et) {
        const int e_row = et * 16 + lr;
        short8 bfrag[4];
        #pragma unroll
        for (int ks = 0; ks < 4; ++ks) {
            int k0 = ks * 32 + lg * 8;
            int off = (e_row * 256 + k0 * 2) ^ ((e_row & 7) << 4);
            bfrag[ks] = *(const short8*)(A_lds + off);
        }
        f32x4 acc[2];
        acc[0] = (f32x4){0.f, 0.f, 0.f, 0.f};
        acc[1] = (f32x4){0.f, 0.f, 0.f, 0.f};
        #pragma unroll
        for (int ks = 0; ks < 4; ++ks) {
            #pragma unroll
            for (int nt = 0; nt < 2; ++nt)
                acc[nt] = __builtin_amdgcn_mfma_f32_16x16x32_bf16(
                    wfrag[nt][ks], bfrag[ks], acc[nt], 0, 0, 0);
        }

        // ---- epilogue for this 16-edge tile ----
        const int el = e_row;            // col = lane&15 = edge within block
        const int e = e0 + el;
        const int zs = zs_s[el], zd = zd_s[el];
        #pragma unroll
        for (int nt = 0; nt < 2; ++nt) {
            int n4 = w * 32 + nt * 16 + lg * 4;
            const float4 p1 = *(const float4*)(P1 + zs * EMB + n4);
            const float4 p2 = *(const float4*)(P2 + zd * EMB + n4);
            float4 o;
            o.x = silu_f(acc[nt][0] + p1.x + p2.x);
            o.y = silu_f(acc[nt][1] + p1.y + p2.y);
            o.z = silu_f(acc[nt][2] + p1.z + p2.z);
            o.w = silu_f(acc[nt][3] + p1.w + p2.w);
            if (e < E) *(float4*)(out_m + (size_t)e * EMB + n4) = o;
        }
    }
}

extern "C" void kernel_launch(void* const* d_in, const int* in_sizes, int n_in,
                              void* d_out, int out_size, void* d_ws, size_t ws_size,
                              hipStream_t stream) {
    const int* Z = (const int*)d_in[0];
    const int* src = (const int*)d_in[1];
    const int* dst = (const int*)d_in[2];
    const float* rbf = (const float*)d_in[3];
    const float* dvec = (const float*)d_in[4];
    const float* emb = (const float*)d_in[5];
    const float* Wr = (const float*)d_in[6];
    const float* brbf = (const float*)d_in[7];
    const float* Wd = (const float*)d_in[8];
    const float* bd = (const float*)d_in[9];

    const int N = in_sizes[0];
    const int E = in_sizes[1];

    float* out_h = (float*)d_out;
    float* out_m = out_h + (size_t)N * EMB;
    float* out_env = out_m + (size_t)E * EMB;

    // workspace: P1 (95*128 f32) | P2 (95*128 f32) | W3 bf16 (128*128)
    float* P1 = (float*)d_ws;
    float* P2 = P1 + NTYPES * EMB;
    unsigned short* W3b = (unsigned short*)(P2 + NTYPES * EMB);

    prep_kernel<<<2 * NTYPES + 8, 128, 0, stream>>>(emb, Wd, bd, P1, P2, W3b);

    int hblocks = (N * (EMB / 4) + 255) / 256;
    h_kernel<<<hblocks, 256, 0, stream>>>(Z, emb, out_h, N);

    int eblocks = (E + 63) / 64;
    edge_kernel<<<eblocks, 256, 0, stream>>>(Z, src, dst, rbf, dvec, Wr, brbf,
                                             P1, P2, W3b, out_m, out_env, E);
}

// Round 3
// 218.516 us; speedup vs baseline: 1.2755x; 1.0824x over previous
//
#include <hip/hip_runtime.h>
#include <hip/hip_bf16.h>
#include <math.h>

#define CUTOFFV 5.0f
#define NRAD 6
#define EMB 128
#define NTYPES 95
#define PI_F 3.14159265358979323846f

typedef short short8 __attribute__((ext_vector_type(8)));
typedef float f32x4 __attribute__((ext_vector_type(4)));

__device__ __forceinline__ unsigned short f2bf(float f) {
    union { float f; unsigned int u; } v; v.f = f;
    unsigned int u = v.u;
    unsigned int r = (u + 0x7FFFu + ((u >> 16) & 1u)) >> 16;
    return (unsigned short)r;
}

__device__ __forceinline__ float fast_rcp(float x) {
    float y;
    asm("v_rcp_f32 %0, %1" : "=v"(y) : "v"(x));
    return y;
}

// silu via hardware rcp (1 ulp) instead of precise-division sequence
__device__ __forceinline__ float silu_f(float x) {
    return x * fast_rcp(1.0f + __expf(-x));
}

__device__ __forceinline__ float rdlane(float v, int l) {
    return __int_as_float(__builtin_amdgcn_readlane(__float_as_int(v), l));
}

// ---- prep: P1 = emb@W1^T + b_dense, P2 = emb@W2^T, W3 -> bf16, Wrp pack ----
__global__ void prep_kernel(const float* __restrict__ emb,
                            const float* __restrict__ Wd,
                            const float* __restrict__ bd,
                            const float* __restrict__ Wr,
                            const float* __restrict__ brbf,
                            float* __restrict__ P1, float* __restrict__ P2,
                            unsigned short* __restrict__ W3b,
                            float* __restrict__ Wrp) {
    int b = blockIdx.x, tid = threadIdx.x;
    if (b < 2 * NTYPES) {
        int t = b / NTYPES, z = b % NTYPES;
        __shared__ float emb_s[EMB];
        emb_s[tid] = emb[z * EMB + tid];
        __syncthreads();
        float acc = (t == 0) ? bd[tid] : 0.0f;
        const float* wrow = Wd + (size_t)tid * 384 + t * EMB;
        #pragma unroll 8
        for (int j = 0; j < EMB; ++j) acc += emb_s[j] * wrow[j];
        (t == 0 ? P1 : P2)[z * EMB + tid] = acc;
    } else if (b < 2 * NTYPES + 8) {
        int g = (b - 2 * NTYPES) * 128 + tid;   // 0..1023
        for (int i = g; i < EMB * EMB; i += 8 * 128) {
            int n = i >> 7, k = i & 127;
            W3b[i] = f2bf(Wd[(size_t)n * 384 + 256 + k]);
        }
    } else {
        // Wrp[k][8] = {w0..w5, bias, 0}
        if (tid < EMB) {
            int k = tid;
            #pragma unroll
            for (int j = 0; j < 6; ++j) Wrp[k * 8 + j] = Wr[k * 6 + j];
            Wrp[k * 8 + 6] = brbf[k];
            Wrp[k * 8 + 7] = 0.0f;
        }
    }
}

// ---------------- h output: gather rows of emb_table --------------------------
__global__ void h_kernel(const int* __restrict__ Z, const float* __restrict__ emb,
                         float* __restrict__ out_h, int N) {
    int idx = blockIdx.x * 256 + threadIdx.x;  // float4 index
    int total = N * (EMB / 4);
    if (idx >= total) return;
    int v = idx >> 5, c = idx & 31;            // 32 float4 per row
    int z = Z[v];
    const float4* e4 = (const float4*)emb;
    float4* o4 = (float4*)out_h;
    o4[idx] = e4[z * 32 + c];
}

// ------- persistent edge kernel: grid-stride over 64-edge tiles ---------------
__global__ void __launch_bounds__(256, 4)
edge_kernel(const int* __restrict__ Z, const int* __restrict__ src,
            const int* __restrict__ dst, const float* __restrict__ rbf,
            const float* __restrict__ dvec,
            const float* __restrict__ P1, const float* __restrict__ P2,
            const unsigned short* __restrict__ W3b,
            const float* __restrict__ Wrp,
            float* __restrict__ out_m, float* __restrict__ out_env,
            int E, int ntiles) {
    __shared__ unsigned char A_lds[64 * 256];   // bf16 [64 edge][128 k], swizzled
    __shared__ int zs_s[64], zd_s[64];

    const int tid = threadIdx.x;
    const int lane = tid & 63;
    const int w = tid >> 6;          // wave id
    const int lr = lane & 15;
    const int lg = lane >> 4;

    // ---- per-block (loop-invariant) register caches ----
    // Wr slice for this wave's k in [32w,32w+32): lane j holds Wrp4[w*64+j]
    const float4 cw = ((const float4*)Wrp)[tid];

    // W3 fragments: wave w owns n in [32w, 32w+32)
    short8 wfrag[2][4];
    #pragma unroll
    for (int nt = 0; nt < 2; ++nt) {
        int n = w * 32 + nt * 16 + lr;
        #pragma unroll
        for (int ks = 0; ks < 4; ++ks)
            wfrag[nt][ks] = *(const short8*)(W3b + n * EMB + ks * 32 + lg * 8);
    }

    for (int t = blockIdx.x; t < ntiles; t += gridDim.x) {
        const int e0 = t * 64;

        // ---- zs/zd gather + rbf_env (tid<64), overlaps producer ----
        if (tid < 64) {
            int e = e0 + tid;
            int ec = (e < E) ? e : (E - 1);
            zs_s[tid] = Z[src[ec]];
            zd_s[tid] = Z[dst[ec]];
            if (e < E) {
                float x = dvec[e] * (1.0f / CUTOFFV);   // (0,1]
                float inv = fast_rcp(x);
                float x2 = x * x;
                float x5 = x2 * x2 * x;
                float env = inv + x5 * (-28.0f + x * (48.0f - 21.0f * x));
                float s1, c1;
                __sincosf(PI_F * x, &s1, &c1);
                float twoc = 2.0f * c1;
                float f = env * inv;
                float s2 = twoc * s1;
                float s3 = twoc * s2 - s1;
                float s4 = twoc * s3 - s2;
                float s5 = twoc * s4 - s3;
                float s6 = twoc * s5 - s4;
                float2* o2 = (float2*)(out_env + (size_t)e * 6);
                o2[0] = make_float2(f * s1, f * s2);
                o2[1] = make_float2(f * s3, f * s4);
                o2[2] = make_float2(f * s5, f * s6);
            }
        }

        // ---- producer: edge = lane, wave w computes k in [32w, 32w+32) ----
        {
            int ecl = e0 + lane;
            if (ecl >= E) ecl = E - 1;
            const float2* rb2 = (const float2*)(rbf + (size_t)ecl * 6);
            const float2 ra = rb2[0], rb = rb2[1], rc = rb2[2];
            #pragma unroll
            for (int c = 0; c < 4; ++c) {
                short8 pk;
                #pragma unroll
                for (int j = 0; j < 8; ++j) {
                    const int ln = 2 * (c * 8 + j);     // compile-time constant
                    float w0 = rdlane(cw.x, ln),     w1 = rdlane(cw.y, ln);
                    float w2 = rdlane(cw.z, ln),     w3v = rdlane(cw.w, ln);
                    float w4 = rdlane(cw.x, ln + 1), w5 = rdlane(cw.y, ln + 1);
                    float bs = rdlane(cw.z, ln + 1);
                    float pre = bs + ra.x * w0 + ra.y * w1 + rb.x * w2 +
                                rb.y * w3v + rc.x * w4 + rc.y * w5;
                    pk[j] = (short)f2bf(silu_f(pre));
                }
                int k0 = w * 32 + c * 8;
                int off = (lane * 256 + k0 * 2) ^ ((lane & 7) << 4);
                *(short8*)(A_lds + off) = pk;
            }
        }
        __syncthreads();

        // ---- MFMA consumer: D[n, edge] = W3[n,:] . rbfproj[edge,:] ----
        #pragma unroll
        for (int et = 0; et < 4; ++et) {
            const int e_row = et * 16 + lr;
            short8 bfrag[4];
            #pragma unroll
            for (int ks = 0; ks < 4; ++ks) {
                int off = (e_row * 256 + (ks * 32 + lg * 8) * 2) ^ ((e_row & 7) << 4);
                bfrag[ks] = *(const short8*)(A_lds + off);
            }
            f32x4 acc[2];
            acc[0] = (f32x4){0.f, 0.f, 0.f, 0.f};
            acc[1] = (f32x4){0.f, 0.f, 0.f, 0.f};
            #pragma unroll
            for (int ks = 0; ks < 4; ++ks)
                #pragma unroll
                for (int nt = 0; nt < 2; ++nt)
                    acc[nt] = __builtin_amdgcn_mfma_f32_16x16x32_bf16(
                        wfrag[nt][ks], bfrag[ks], acc[nt], 0, 0, 0);

            // epilogue: lane holds 4 consecutive n for ONE edge -> float4 I/O
            const int el = e_row;
            const int e = e0 + el;
            const int zs = zs_s[el], zd = zd_s[el];
            #pragma unroll
            for (int nt = 0; nt < 2; ++nt) {
                int n4 = w * 32 + nt * 16 + lg * 4;
                const float4 p1 = *(const float4*)(P1 + zs * EMB + n4);
                const float4 p2 = *(const float4*)(P2 + zd * EMB + n4);
                float4 o;
                o.x = silu_f(acc[nt][0] + p1.x + p2.x);
                o.y = silu_f(acc[nt][1] + p1.y + p2.y);
                o.z = silu_f(acc[nt][2] + p1.z + p2.z);
                o.w = silu_f(acc[nt][3] + p1.w + p2.w);
                if (e < E) *(float4*)(out_m + (size_t)e * EMB + n4) = o;
            }
        }
        __syncthreads();   // protect A_lds / zs_s before next tile's producer
    }
}

extern "C" void kernel_launch(void* const* d_in, const int* in_sizes, int n_in,
                              void* d_out, int out_size, void* d_ws, size_t ws_size,
                              hipStream_t stream) {
    const int* Z = (const int*)d_in[0];
    const int* src = (const int*)d_in[1];
    const int* dst = (const int*)d_in[2];
    const float* rbf = (const float*)d_in[3];
    const float* dvec = (const float*)d_in[4];
    const float* emb = (const float*)d_in[5];
    const float* Wr = (const float*)d_in[6];
    const float* brbf = (const float*)d_in[7];
    const float* Wd = (const float*)d_in[8];
    const float* bd = (const float*)d_in[9];

    const int N = in_sizes[0];
    const int E = in_sizes[1];

    float* out_h = (float*)d_out;
    float* out_m = out_h + (size_t)N * EMB;
    float* out_env = out_m + (size_t)E * EMB;

    // workspace: P1 | P2 (95*128 f32 each) | W3 bf16 (128*128) | Wrp (128*8 f32)
    float* P1 = (float*)d_ws;
    float* P2 = P1 + NTYPES * EMB;
    unsigned short* W3b = (unsigned short*)(P2 + NTYPES * EMB);
    float* Wrp = (float*)(W3b + EMB * EMB);

    prep_kernel<<<2 * NTYPES + 9, 128, 0, stream>>>(emb, Wd, bd, Wr, brbf,
                                                    P1, P2, W3b, Wrp);

    int hblocks = (N * (EMB / 4) + 255) / 256;
    h_kernel<<<hblocks, 256, 0, stream>>>(Z, emb, out_h, N);

    int ntiles = (E + 63) / 64;
    int grid = ntiles < 1024 ? ntiles : 1024;
    edge_kernel<<<grid, 256, 0, stream>>>(Z, src, dst, rbf, dvec,
                                          P1, P2, W3b, Wrp,
                                          out_m, out_env, E, ntiles);
}

// Round 5
// 174.544 us; speedup vs baseline: 1.5969x; 1.2519x over previous
//
#include <hip/hip_runtime.h>
#include <hip/hip_bf16.h>
#include <math.h>

#define CUTOFFV 5.0f
#define NRAD 6
#define EMB 128
#define NTYPES 95
#define PI_F 3.14159265358979323846f

typedef short short8 __attribute__((ext_vector_type(8)));
typedef float f32x4 __attribute__((ext_vector_type(4)));
typedef float f32x2 __attribute__((ext_vector_type(2)));

__device__ __forceinline__ unsigned short f2bf(float f) {
    union { float f; unsigned int u; } v; v.f = f;
    unsigned int u = v.u;
    unsigned int r = (u + 0x7FFFu + ((u >> 16) & 1u)) >> 16;
    return (unsigned short)r;
}

__device__ __forceinline__ float fast_rcp(float x) {
    float y;
    asm("v_rcp_f32 %0, %1" : "=v"(y) : "v"(x));
    return y;
}

// silu via hardware rcp (1 ulp) instead of precise-division sequence
__device__ __forceinline__ float silu_f(float x) {
    return x * fast_rcp(1.0f + __expf(-x));
}

__device__ __forceinline__ float rdlane(float v, int l) {
    return __int_as_float(__builtin_amdgcn_readlane(__float_as_int(v), l));
}

// ---- prep: P1 = emb@W1^T + b_dense, P2 = emb@W2^T, W3 -> bf16, Wrp pack ----
__global__ void prep_kernel(const float* __restrict__ emb,
                            const float* __restrict__ Wd,
                            const float* __restrict__ bd,
                            const float* __restrict__ Wr,
                            const float* __restrict__ brbf,
                            float* __restrict__ P1, float* __restrict__ P2,
                            unsigned short* __restrict__ W3b,
                            float* __restrict__ Wrp) {
    int b = blockIdx.x, tid = threadIdx.x;
    if (b < 2 * NTYPES) {
        int t = b / NTYPES, z = b % NTYPES;
        __shared__ float emb_s[EMB];
        emb_s[tid] = emb[z * EMB + tid];
        __syncthreads();
        float acc = (t == 0) ? bd[tid] : 0.0f;
        const float* wrow = Wd + (size_t)tid * 384 + t * EMB;
        #pragma unroll 8
        for (int j = 0; j < EMB; ++j) acc += emb_s[j] * wrow[j];
        (t == 0 ? P1 : P2)[z * EMB + tid] = acc;
    } else if (b < 2 * NTYPES + 8) {
        int g = (b - 2 * NTYPES) * 128 + tid;   // 0..1023
        for (int i = g; i < EMB * EMB; i += 8 * 128) {
            int n = i >> 7, k = i & 127;
            W3b[i] = f2bf(Wd[(size_t)n * 384 + 256 + k]);
        }
    } else {
        // Wrp[k][8] = {w0..w5, bias, 0}
        if (tid < EMB) {
            int k = tid;
            #pragma unroll
            for (int j = 0; j < 6; ++j) Wrp[k * 8 + j] = Wr[k * 6 + j];
            Wrp[k * 8 + 6] = brbf[k];
            Wrp[k * 8 + 7] = 0.0f;
        }
    }
}

// ---------------- h output: gather rows of emb_table --------------------------
__global__ void h_kernel(const int* __restrict__ Z, const float* __restrict__ emb,
                         float* __restrict__ out_h, int N) {
    int idx = blockIdx.x * 256 + threadIdx.x;  // float4 index
    int total = N * (EMB / 4);
    if (idx >= total) return;
    int v = idx >> 5, c = idx & 31;            // 32 float4 per row
    int z = Z[v];
    const f32x4* e4 = (const f32x4*)emb;
    f32x4* o4 = (f32x4*)out_h;
    o4[idx] = e4[z * 32 + c];
}

// -- persistent edge kernel: software-pipelined, 1 barrier/tile, dbuf LDS ------
__global__ void __launch_bounds__(256, 4)
edge_kernel(const int* __restrict__ Z, const int* __restrict__ src,
            const int* __restrict__ dst, const float* __restrict__ rbf,
            const float* __restrict__ dvec,
            const float* __restrict__ P1, const float* __restrict__ P2,
            const unsigned short* __restrict__ W3b,
            const float* __restrict__ Wrp,
            float* __restrict__ out_m, float* __restrict__ out_env,
            int E, int ntiles) {
    __shared__ unsigned char A_lds[2][64 * 256]; // bf16 [edge][k], swizzled
    __shared__ int zs_s[2][64], zd_s[2][64];

    const int tid = threadIdx.x;
    const int lane = tid & 63;
    const int w = tid >> 6;          // wave id
    const int lr = lane & 15;
    const int lg = lane >> 4;

    // ---- per-block (loop-invariant) register caches ----
    const f32x4 cw = ((const f32x4*)Wrp)[tid];

    short8 wfrag[2][4];
    #pragma unroll
    for (int nt = 0; nt < 2; ++nt) {
        int n = w * 32 + nt * 16 + lr;
        #pragma unroll
        for (int ks = 0; ks < 4; ++ks)
            wfrag[nt][ks] = *(const short8*)(W3b + n * EMB + ks * 32 + lg * 8);
    }

    for (int i = 0; ; ++i) {
        const int tp = blockIdx.x + i * gridDim.x;   // tile to produce
        const int tc = tp - gridDim.x;               // tile to consume (prev it)
        const bool do_p = (tp < ntiles);
        const bool do_c = (i > 0) && (tc < ntiles);
        if (!do_p && !do_c) break;
        const int pi = i & 1, ci = pi ^ 1;

        // ---- A: issue produce-tile global loads (consumed after B) ----
        f32x2 ra = {0.f, 0.f}, rb = {0.f, 0.f}, rc = {0.f, 0.f};
        float dv = 0.0f;
        int srcv = 0, dstv = 0;
        if (do_p) {
            const int e0p = tp * 64;
            int ecl = e0p + lane; if (ecl >= E) ecl = E - 1;
            const f32x2* r2 = (const f32x2*)(rbf + (size_t)ecl * 6);
            ra = r2[0]; rb = r2[1]; rc = r2[2];
            if (tid < 64) {
                int ec = (e0p + tid < E) ? (e0p + tid) : (E - 1);
                srcv = src[ec]; dstv = dst[ec];
                dv = dvec[ec];
            }
        }

        // ---- B: consume tile tc (MFMA + epilogue; hides A's latency) ----
        if (do_c) {
            const int e0c = tc * 64;
            const unsigned char* Ab = A_lds[ci];
            #pragma unroll
            for (int et = 0; et < 4; ++et) {
                const int e_row = et * 16 + lr;
                short8 bfrag[4];
                #pragma unroll
                for (int ks = 0; ks < 4; ++ks) {
                    int off = (e_row * 256 + (ks * 32 + lg * 8) * 2) ^ ((e_row & 7) << 4);
                    bfrag[ks] = *(const short8*)(Ab + off);
                }
                f32x4 acc[2];
                acc[0] = (f32x4){0.f, 0.f, 0.f, 0.f};
                acc[1] = (f32x4){0.f, 0.f, 0.f, 0.f};
                #pragma unroll
                for (int ks = 0; ks < 4; ++ks)
                    #pragma unroll
                    for (int nt = 0; nt < 2; ++nt)
                        acc[nt] = __builtin_amdgcn_mfma_f32_16x16x32_bf16(
                            wfrag[nt][ks], bfrag[ks], acc[nt], 0, 0, 0);

                const int el = e_row;
                const int e = e0c + el;
                const int zs = zs_s[ci][el], zd = zd_s[ci][el];
                #pragma unroll
                for (int nt = 0; nt < 2; ++nt) {
                    int n4 = w * 32 + nt * 16 + lg * 4;
                    const f32x4 p1 = *(const f32x4*)(P1 + zs * EMB + n4);
                    const f32x4 p2 = *(const f32x4*)(P2 + zd * EMB + n4);
                    f32x4 o;
                    o.x = silu_f(acc[nt][0] + p1.x + p2.x);
                    o.y = silu_f(acc[nt][1] + p1.y + p2.y);
                    o.z = silu_f(acc[nt][2] + p1.z + p2.z);
                    o.w = silu_f(acc[nt][3] + p1.w + p2.w);
                    if (e < E)
                        __builtin_nontemporal_store(
                            o, (f32x4*)(out_m + (size_t)e * EMB + n4));
                }
            }
        }

        if (do_p) {
            const int e0p = tp * 64;

            // ---- C: env + issue Z gathers (latency hidden under D) ----
            int zsr = 0, zdr = 0;
            if (tid < 64) {
                zsr = Z[srcv]; zdr = Z[dstv];
                int e = e0p + tid;
                if (e < E) {
                    float x = dv * (1.0f / CUTOFFV);   // (0,1]
                    float inv = fast_rcp(x);
                    float x2 = x * x;
                    float x5 = x2 * x2 * x;
                    float env = inv + x5 * (-28.0f + x * (48.0f - 21.0f * x));
                    float s1, c1;
                    __sincosf(PI_F * x, &s1, &c1);
                    float twoc = 2.0f * c1;
                    float f = env * inv;
                    float s2 = twoc * s1;
                    float s3 = twoc * s2 - s1;
                    float s4 = twoc * s3 - s2;
                    float s5 = twoc * s4 - s3;
                    float s6 = twoc * s5 - s4;
                    float* o = out_env + (size_t)e * 6;
                    __builtin_nontemporal_store((f32x2){f * s1, f * s2}, (f32x2*)o);
                    __builtin_nontemporal_store((f32x2){f * s3, f * s4}, (f32x2*)(o + 2));
                    __builtin_nontemporal_store((f32x2){f * s5, f * s6}, (f32x2*)(o + 4));
                }
            }

            // ---- D: producer (VALU-heavy): edge=lane, wave w -> k slice ----
            #pragma unroll
            for (int c = 0; c < 4; ++c) {
                short8 pk;
                #pragma unroll
                for (int j = 0; j < 8; ++j) {
                    const int ln = 2 * (c * 8 + j);     // compile-time constant
                    float w0 = rdlane(cw.x, ln),     w1 = rdlane(cw.y, ln);
                    float w2 = rdlane(cw.z, ln),     w3v = rdlane(cw.w, ln);
                    float w4 = rdlane(cw.x, ln + 1), w5 = rdlane(cw.y, ln + 1);
                    float bs = rdlane(cw.z, ln + 1);
                    float pre = bs + ra.x * w0 + ra.y * w1 + rb.x * w2 +
                                rb.y * w3v + rc.x * w4 + rc.y * w5;
                    pk[j] = (short)f2bf(silu_f(pre));
                }
                int k0 = w * 32 + c * 8;
                int off = (lane * 256 + k0 * 2) ^ ((lane & 7) << 4);
                *(short8*)(A_lds[pi] + off) = pk;
            }

            // ---- E: stash z indices for next iteration's consumer ----
            if (tid < 64) {
                zs_s[pi][tid] = zsr;
                zd_s[pi][tid] = zdr;
            }
        }

        __syncthreads();   // single barrier per tile
    }
}

extern "C" void kernel_launch(void* const* d_in, const int* in_sizes, int n_in,
                              void* d_out, int out_size, void* d_ws, size_t ws_size,
                              hipStream_t stream) {
    const int* Z = (const int*)d_in[0];
    const int* src = (const int*)d_in[1];
    const int* dst = (const int*)d_in[2];
    const float* rbf = (const float*)d_in[3];
    const float* dvec = (const float*)d_in[4];
    const float* emb = (const float*)d_in[5];
    const float* Wr = (const float*)d_in[6];
    const float* brbf = (const float*)d_in[7];
    const float* Wd = (const float*)d_in[8];
    const float* bd = (const float*)d_in[9];

    const int N = in_sizes[0];
    const int E = in_sizes[1];

    float* out_h = (float*)d_out;
    float* out_m = out_h + (size_t)N * EMB;
    float* out_env = out_m + (size_t)E * EMB;

    // workspace: P1 | P2 (95*128 f32 each) | W3 bf16 (128*128) | Wrp (128*8 f32)
    float* P1 = (float*)d_ws;
    float* P2 = P1 + NTYPES * EMB;
    unsigned short* W3b = (unsigned short*)(P2 + NTYPES * EMB);
    float* Wrp = (float*)(W3b + EMB * EMB);

    prep_kernel<<<2 * NTYPES + 9, 128, 0, stream>>>(emb, Wd, bd, Wr, brbf,
                                                    P1, P2, W3b, Wrp);

    int hblocks = (N * (EMB / 4) + 255) / 256;
    h_kernel<<<hblocks, 256, 0, stream>>>(Z, emb, out_h, N);

    int ntiles = (E + 63) / 64;
    int grid = ntiles < 1024 ? ntiles : 1024;
    edge_kernel<<<grid, 256, 0, stream>>>(Z, src, dst, rbf, dvec,
                                          P1, P2, W3b, Wrp,
                                          out_m, out_env, E, ntiles);
}